// Round 2
// baseline (700.057 us; speedup 1.0000x reference)
//
#include <hip/hip_runtime.h>

typedef __attribute__((ext_vector_type(4))) float fv4;
typedef __attribute__((ext_vector_type(8))) _Float16 hv8;
typedef __attribute__((ext_vector_type(4))) _Float16 hv4;

// ---------------------------------------------------------------------------
// async global->LDS 16B copy (wave-uniform LDS base + lane*16 semantics)
// ---------------------------------------------------------------------------
__device__ __forceinline__ void gload16(const void* g, void* l) {
  __builtin_amdgcn_global_load_lds(
      (const __attribute__((address_space(1))) unsigned int*)g,
      (__attribute__((address_space(3))) unsigned int*)l, 16, 0, 0);
}

// ---------------------------------------------------------------------------
// GEMM: C[M,N] (OutT, + bias) = A[M,K] (f16, row-major) @ Bt[N,K]^T
// 128x128 tile, BK=32, 4 waves (2x2), per-wave 4x4 tiles of 16x16x32 MFMA.
// M mult of 128, N mult of 128, K mult of 32. ldc == N.
// ---------------------------------------------------------------------------
template <typename OutT>
__global__ __launch_bounds__(256)
void gemm_f16_bt(const _Float16* __restrict__ A, const _Float16* __restrict__ Bt,
                 OutT* __restrict__ C, const float* __restrict__ bias,
                 int N, int K) {
  __shared__ _Float16 lds[2 * 128 * 32];
  _Float16* ldsA = lds;
  _Float16* ldsB = lds + 128 * 32;

  const int tid  = threadIdx.x;
  const int lane = tid & 63;
  const int wave = tid >> 6;
  const int wm   = wave >> 1;
  const int wn   = wave & 1;
  const int quad = lane >> 4;
  const int r    = lane & 15;

  const int m0 = blockIdx.y * 128;
  const int n0 = blockIdx.x * 128;

  const _Float16* ap0 = A  + (size_t)(m0 + (tid >> 2)) * K + (tid & 3) * 8;
  const _Float16* bp0 = Bt + (size_t)(n0 + (tid >> 2)) * K + (tid & 3) * 8;
  const size_t half = (size_t)64 * K;

  _Float16* dA0 = ldsA + wave * 512;
  _Float16* dA1 = ldsA + wave * 512 + 2048;
  _Float16* dB0 = ldsB + wave * 512;
  _Float16* dB1 = ldsB + wave * 512 + 2048;

  const _Float16* fa = ldsA + (wm * 64 + r) * 32 + quad * 8;
  const _Float16* fb = ldsB + (wn * 64 + r) * 32 + quad * 8;

  fv4 acc[4][4] = {};

  const int kiters = K >> 5;
  for (int kk = 0; kk < kiters; ++kk) {
    gload16(ap0,        dA0);
    gload16(ap0 + half, dA1);
    gload16(bp0,        dB0);
    gload16(bp0 + half, dB1);
    ap0 += 32; bp0 += 32;
    __syncthreads();   // drains vmcnt -> LDS tiles complete

    hv8 av[4], bv[4];
#pragma unroll
    for (int t = 0; t < 4; ++t) {
      av[t] = *(const hv8*)(fa + t * 512);
      bv[t] = *(const hv8*)(fb + t * 512);
    }
#pragma unroll
    for (int tm = 0; tm < 4; ++tm) {
#pragma unroll
      for (int tn = 0; tn < 4; ++tn) {
        acc[tm][tn] = __builtin_amdgcn_mfma_f32_16x16x32_f16(av[tm], bv[tn],
                                                             acc[tm][tn], 0, 0, 0);
      }
    }
    __syncthreads();
  }

  // C/D layout: col = lane&15, row = quad*4 + reg  (m89-verified)
  const int col0 = n0 + wn * 64 + r;
  const int row0 = m0 + wm * 64 + quad * 4;
#pragma unroll
  for (int tn = 0; tn < 4; ++tn) {
    const int col = col0 + tn * 16;
    const float bs = bias[col];
#pragma unroll
    for (int tm = 0; tm < 4; ++tm) {
#pragma unroll
      for (int r2 = 0; r2 < 4; ++r2) {
        C[(size_t)(row0 + tm * 16 + r2) * N + col] = (OutT)(acc[tm][tn][r2] + bs);
      }
    }
  }
}

// ---------------------------------------------------------------------------
// elementwise fp32 -> f16
// ---------------------------------------------------------------------------
__global__ void cvt_f16(const float* __restrict__ x, _Float16* __restrict__ y) {
  size_t i = ((size_t)blockIdx.x * 256 + threadIdx.x) * 4;
  fv4 v = *(const fv4*)(x + i);
  *(hv4*)(y + i) = __builtin_convertvector(v, hv4);
}

// ---------------------------------------------------------------------------
// W[K,N] fp32 -> Wt[N,K] f16 (LDS-tiled transpose; K,N multiples of 32)
// ---------------------------------------------------------------------------
__global__ void transpose_cvt(const float* __restrict__ W, _Float16* __restrict__ Wt,
                              int K, int N) {
  __shared__ float tile[32][33];
  const int tx = threadIdx.x, ty = threadIdx.y;
  const int n  = blockIdx.x * 32 + tx;
  const int kb = blockIdx.y * 32;
  for (int i = ty; i < 32; i += 8)
    tile[i][tx] = W[(size_t)(kb + i) * N + n];
  __syncthreads();
  const int k = kb + tx;
  for (int i = ty; i < 32; i += 8)
    Wt[(size_t)(blockIdx.x * 32 + i) * K + k] = (_Float16)tile[tx][i];
}

// ---------------------------------------------------------------------------
// bias concat: out[0:1024]=bz0, [1024:2048]=bh0, [2048:3072]=bz1, [3072:4096]=bh1
// ---------------------------------------------------------------------------
__global__ void concat_bias(const float* __restrict__ bz0, const float* __restrict__ bh0,
                            const float* __restrict__ bz1, const float* __restrict__ bh1,
                            float* __restrict__ out) {
  const int i = blockIdx.x * 256 + threadIdx.x;  // 4096 threads
  float v;
  if (i < 1024)      v = bz0[i];
  else if (i < 2048) v = bh0[i - 1024];
  else if (i < 3072) v = bz1[i - 2048];
  else               v = bh1[i - 3072];
  out[i] = v;
}

// ---------------------------------------------------------------------------
// gate (in place on zh [M,2048] f16): z-half <- a = 1-sigmoid(zpre),
//                                     h-half <- b = sigmoid(zpre)*hpre
// ---------------------------------------------------------------------------
__global__ void gate_f16(_Float16* __restrict__ zh) {
  const int idx = blockIdx.x * 256 + threadIdx.x;  // M*H/4 = 8388608
  const int h   = (idx & 255) * 4;
  const size_t row = (size_t)(idx >> 8);
  _Float16* pz = zh + row * 2048 + h;
  _Float16* ph = pz + 1024;
  fv4 zp = __builtin_convertvector(*(const hv4*)pz, fv4);
  fv4 hp = __builtin_convertvector(*(const hv4*)ph, fv4);
  fv4 z;
  z.x = 1.0f / (1.0f + __expf(-zp.x));
  z.y = 1.0f / (1.0f + __expf(-zp.y));
  z.z = 1.0f / (1.0f + __expf(-zp.z));
  z.w = 1.0f / (1.0f + __expf(-zp.w));
  const fv4 one = {1.0f, 1.0f, 1.0f, 1.0f};
  *(hv4*)pz = __builtin_convertvector(one - z, hv4);
  *(hv4*)ph = __builtin_convertvector(z * hp, hv4);
}

// ---------------------------------------------------------------------------
// chunked scan, T=4096 as 64 chunks of 64, per (b,h). a,b live in zh (f16).
// phase A: per-chunk composition (A = prod a, Bv = chunk result from h_in=0)
// ---------------------------------------------------------------------------
__global__ void scan_phaseA(const _Float16* __restrict__ zh,
                            float* __restrict__ cA, float* __restrict__ cB) {
  const int idx = blockIdx.x * 256 + threadIdx.x;  // B*64*(H/4) = 131072
  const int h  = (idx & 255) * 4;
  const int c  = (idx >> 8) & 63;
  const int bb = idx >> 14;
  const size_t base = (size_t)(bb * 4096 + c * 64) * 2048 + h;
  fv4 Aa = {1.0f, 1.0f, 1.0f, 1.0f};
  fv4 Bv = {0.0f, 0.0f, 0.0f, 0.0f};
#pragma unroll 4
  for (int t = 0; t < 64; ++t) {
    fv4 av = __builtin_convertvector(*(const hv4*)(zh + base + (size_t)t * 2048), fv4);
    fv4 bv = __builtin_convertvector(*(const hv4*)(zh + base + 1024 + (size_t)t * 2048), fv4);
    Aa = Aa * av;
    Bv = av * Bv + bv;
  }
  const size_t o = (size_t)(bb * 64 + c) * 1024 + h;
  *(fv4*)(cA + o) = Aa;
  *(fv4*)(cB + o) = Bv;
}

// phase B: sequential prefix over the 64 chunks; hcy[c] = h entering chunk c
__global__ void scan_phaseB(const float* __restrict__ cA, const float* __restrict__ cB,
                            float* __restrict__ hcy) {
  const int idx = blockIdx.x * 256 + threadIdx.x;  // B*(H/4) = 2048
  const int h  = (idx & 255) * 4;
  const int bb = idx >> 8;
  fv4 hc = {0.0f, 0.0f, 0.0f, 0.0f};
  for (int c = 0; c < 64; ++c) {
    const size_t o = (size_t)(bb * 64 + c) * 1024 + h;
    *(fv4*)(hcy + o) = hc;
    fv4 Aa = *(const fv4*)(cA + o);
    fv4 Bv = *(const fv4*)(cB + o);
    hc = Aa * hc + Bv;
  }
}

// phase C: replay chunk with correct carry, emit h (f16, [M,1024])
__global__ void scan_phaseC(const _Float16* __restrict__ zh,
                            const float* __restrict__ hcy,
                            _Float16* __restrict__ hout) {
  const int idx = blockIdx.x * 256 + threadIdx.x;
  const int h  = (idx & 255) * 4;
  const int c  = (idx >> 8) & 63;
  const int bb = idx >> 14;
  const size_t base = (size_t)(bb * 4096 + c * 64) * 2048 + h;
  const size_t ob   = (size_t)(bb * 4096 + c * 64) * 1024 + h;
  const size_t o = (size_t)(bb * 64 + c) * 1024 + h;
  fv4 hc = *(const fv4*)(hcy + o);
#pragma unroll 4
  for (int t = 0; t < 64; ++t) {
    fv4 av = __builtin_convertvector(*(const hv4*)(zh + base + (size_t)t * 2048), fv4);
    fv4 bv = __builtin_convertvector(*(const hv4*)(zh + base + 1024 + (size_t)t * 2048), fv4);
    hc = av * hc + bv;
    *(hv4*)(hout + ob + (size_t)t * 1024) = __builtin_convertvector(hc, hv4);
  }
}

// ---------------------------------------------------------------------------
extern "C" void kernel_launch(void* const* d_in, const int* in_sizes, int n_in,
                              void* d_out, int out_size, void* d_ws, size_t ws_size,
                              hipStream_t stream) {
  const float* x   = (const float*)d_in[0];
  const float* Wz0 = (const float*)d_in[1];
  const float* bz0 = (const float*)d_in[2];
  const float* Wh0 = (const float*)d_in[3];
  const float* bh0 = (const float*)d_in[4];
  const float* Wz1 = (const float*)d_in[5];
  const float* bz1 = (const float*)d_in[6];
  const float* Wh1 = (const float*)d_in[7];
  const float* bh1 = (const float*)d_in[8];
  const float* Wfc = (const float*)d_in[9];
  const float* bfc = (const float*)d_in[10];

  const int Mrows = 32768;  // B*T
  const int H = 1024, Din = 512, Dout = 512;

  // workspace layout (~205 MiB total; lifetimes annotated)
  char* w = (char*)d_ws;
  _Float16* zh    = (_Float16*)w; w += (size_t)Mrows * 2 * H * 2;   // 128 MiB: zpre|hpre -> a|b (per layer)
  _Float16* hx    = (_Float16*)w; w += (size_t)Mrows * H * 2;       //  64 MiB: Xb (f16 x) then h0/h1
  _Float16* Wzh0t = (_Float16*)w; w += (size_t)2 * H * Din * 2;     //   2 MiB
  _Float16* Wzh1t = (_Float16*)w; w += (size_t)2 * H * H * 2;       //   4 MiB
  _Float16* Wft   = (_Float16*)w; w += (size_t)Dout * H * 2;        //   1 MiB
  float*    biasZ = (float*)w;    w += (size_t)4096 * 4;            //  16 KiB
  float*    cA    = (float*)w;    w += (size_t)8 * 64 * H * 4;      //   2 MiB
  float*    cB    = (float*)w;    w += (size_t)8 * 64 * H * 4;      //   2 MiB
  float*    hcy   = (float*)w;    w += (size_t)8 * 64 * H * 4;      //   2 MiB
  _Float16* Xb    = hx;  // aliased: x(f16) dead before h0 is written

  // --- input conversions ---
  cvt_f16<<<Mrows * Din / 1024, 256, 0, stream>>>(x, Xb);
  transpose_cvt<<<dim3(H / 32, Din / 32), dim3(32, 8), 0, stream>>>(Wz0, Wzh0t, Din, H);
  transpose_cvt<<<dim3(H / 32, Din / 32), dim3(32, 8), 0, stream>>>(Wh0, Wzh0t + (size_t)H * Din, Din, H);
  transpose_cvt<<<dim3(H / 32, H / 32),   dim3(32, 8), 0, stream>>>(Wz1, Wzh1t, H, H);
  transpose_cvt<<<dim3(H / 32, H / 32),   dim3(32, 8), 0, stream>>>(Wh1, Wzh1t + (size_t)H * H, H, H);
  transpose_cvt<<<dim3(Dout / 32, H / 32), dim3(32, 8), 0, stream>>>(Wfc, Wft, H, Dout);
  concat_bias<<<16, 256, 0, stream>>>(bz0, bh0, bz1, bh1, biasZ);

  const dim3 gG(2 * H / 128, Mrows / 128);   // fused z|h GEMM, N=2048
  const int gateBlocks = Mrows * H / 1024;

  // --- layer 0 ---
  gemm_f16_bt<_Float16><<<gG, 256, 0, stream>>>(Xb, Wzh0t, zh, biasZ, 2 * H, Din);
  gate_f16<<<gateBlocks, 256, 0, stream>>>(zh);
  scan_phaseA<<<512, 256, 0, stream>>>(zh, cA, cB);
  scan_phaseB<<<8, 256, 0, stream>>>(cA, cB, hcy);
  scan_phaseC<<<512, 256, 0, stream>>>(zh, hcy, hx);

  // --- layer 1 ---
  gemm_f16_bt<_Float16><<<gG, 256, 0, stream>>>(hx, Wzh1t, zh, biasZ + 2048, 2 * H, H);
  gate_f16<<<gateBlocks, 256, 0, stream>>>(zh);
  scan_phaseA<<<512, 256, 0, stream>>>(zh, cA, cB);
  scan_phaseB<<<8, 256, 0, stream>>>(cA, cB, hcy);
  scan_phaseC<<<512, 256, 0, stream>>>(zh, hcy, hx);

  // --- FC head ---
  const dim3 gF(Dout / 128, Mrows / 128);
  gemm_f16_bt<float><<<gF, 256, 0, stream>>>(hx, Wft, (float*)d_out, bfc, Dout, H);
}

// Round 3
// 656.350 us; speedup vs baseline: 1.0666x; 1.0666x over previous
//
#include <hip/hip_runtime.h>

typedef __attribute__((ext_vector_type(4))) float fv4;
typedef __attribute__((ext_vector_type(8))) _Float16 hv8;
typedef __attribute__((ext_vector_type(4))) _Float16 hv4;
typedef __attribute__((ext_vector_type(2))) _Float16 hv2;

// ---------------------------------------------------------------------------
// async global->LDS 16B copy (wave-uniform LDS base + lane*16 semantics)
// ---------------------------------------------------------------------------
__device__ __forceinline__ void gload16(const void* g, void* l) {
  __builtin_amdgcn_global_load_lds(
      (const __attribute__((address_space(1))) unsigned int*)g,
      (__attribute__((address_space(3))) unsigned int*)l, 16, 0, 0);
}

// ---------------------------------------------------------------------------
// Fused layer GEMM + minGRU gate.
// A[M,K] f16 row-major; Btf[2048,K] f16 = fused z|h weight, row-reordered so
// GEMM rows [b*64, b*64+32) = Wz cols b*32.., [b*64+32, b*64+64) = Wh cols b*32..
// Epilogue: a = 1-sigmoid(zpre+bz), b = sigmoid(..)*(hpre+bh), stored
// interleaved: zh2[row][j] = (a,b) f16 pair.  N fixed = 2048 GEMM cols.
// ---------------------------------------------------------------------------
__global__ __launch_bounds__(256)
void gemm_gate(const _Float16* __restrict__ A, const _Float16* __restrict__ Btf,
               _Float16* __restrict__ zh2,
               const float* __restrict__ bz, const float* __restrict__ bh,
               int K) {
  __shared__ _Float16 lds[2 * 128 * 32];
  _Float16* ldsA = lds;
  _Float16* ldsB = lds + 128 * 32;

  const int tid  = threadIdx.x;
  const int lane = tid & 63;
  const int wave = tid >> 6;
  const int wm   = wave >> 1;
  const int wn   = wave & 1;
  const int quad = lane >> 4;
  const int r    = lane & 15;

  const int m0 = blockIdx.y * 128;
  const int n0 = blockIdx.x * 128;

  const _Float16* ap0 = A   + (size_t)(m0 + (tid >> 2)) * K + (tid & 3) * 8;
  const _Float16* bp0 = Btf + (size_t)(n0 + (tid >> 2)) * K + (tid & 3) * 8;
  const size_t half = (size_t)64 * K;

  _Float16* dA0 = ldsA + wave * 512;
  _Float16* dA1 = ldsA + wave * 512 + 2048;
  _Float16* dB0 = ldsB + wave * 512;
  _Float16* dB1 = ldsB + wave * 512 + 2048;

  const _Float16* fa = ldsA + (wm * 64 + r) * 32 + quad * 8;
  const _Float16* fb = ldsB + (wn * 64 + r) * 32 + quad * 8;

  fv4 acc[4][4] = {};

  const int kiters = K >> 5;
  for (int kk = 0; kk < kiters; ++kk) {
    gload16(ap0,        dA0);
    gload16(ap0 + half, dA1);
    gload16(bp0,        dB0);
    gload16(bp0 + half, dB1);
    ap0 += 32; bp0 += 32;
    __syncthreads();

    hv8 av[4], bv[4];
#pragma unroll
    for (int t = 0; t < 4; ++t) {
      av[t] = *(const hv8*)(fa + t * 512);
      bv[t] = *(const hv8*)(fb + t * 512);
    }
#pragma unroll
    for (int tm = 0; tm < 4; ++tm) {
#pragma unroll
      for (int tn = 0; tn < 4; ++tn) {
        acc[tm][tn] = __builtin_amdgcn_mfma_f32_16x16x32_f16(av[tm], bv[tn],
                                                             acc[tm][tn], 0, 0, 0);
      }
    }
    __syncthreads();
  }

  // C/D layout: col = lane&15, row = quad*4 + reg (m89-verified).
  // Wave covers GEMM cols [n0+wn*64, +64) = one fused 64-block: tn 0,1 are
  // zpre for j = jb+tn*16+r; tn 2,3 are hpre for the same j.
  const int jb   = (n0 + wn * 64) >> 1;
  const int row0 = m0 + wm * 64 + quad * 4;
#pragma unroll
  for (int tn = 0; tn < 2; ++tn) {
    const int j = jb + tn * 16 + r;
    const float bzv = bz[j];
    const float bhv = bh[j];
#pragma unroll
    for (int tm = 0; tm < 4; ++tm) {
#pragma unroll
      for (int r2 = 0; r2 < 4; ++r2) {
        const float zpre = acc[tm][tn][r2] + bzv;
        const float hpre = acc[tm][tn + 2][r2] + bhv;
        const float z = 1.0f / (1.0f + __expf(-zpre));
        hv2 ab = {(_Float16)(1.0f - z), (_Float16)(z * hpre)};
        *(hv2*)(zh2 + ((size_t)(row0 + tm * 16 + r2) * 1024 + j) * 2) = ab;
      }
    }
  }
}

// ---------------------------------------------------------------------------
// Plain GEMM (FC head): C[M,N] fp32 = A[M,K] f16 @ Bt[N,K]^T + bias
// ---------------------------------------------------------------------------
__global__ __launch_bounds__(256)
void gemm_f16_bt(const _Float16* __restrict__ A, const _Float16* __restrict__ Bt,
                 float* __restrict__ C, const float* __restrict__ bias,
                 int N, int K) {
  __shared__ _Float16 lds[2 * 128 * 32];
  _Float16* ldsA = lds;
  _Float16* ldsB = lds + 128 * 32;

  const int tid  = threadIdx.x;
  const int lane = tid & 63;
  const int wave = tid >> 6;
  const int wm   = wave >> 1;
  const int wn   = wave & 1;
  const int quad = lane >> 4;
  const int r    = lane & 15;

  const int m0 = blockIdx.y * 128;
  const int n0 = blockIdx.x * 128;

  const _Float16* ap0 = A  + (size_t)(m0 + (tid >> 2)) * K + (tid & 3) * 8;
  const _Float16* bp0 = Bt + (size_t)(n0 + (tid >> 2)) * K + (tid & 3) * 8;
  const size_t half = (size_t)64 * K;

  _Float16* dA0 = ldsA + wave * 512;
  _Float16* dA1 = ldsA + wave * 512 + 2048;
  _Float16* dB0 = ldsB + wave * 512;
  _Float16* dB1 = ldsB + wave * 512 + 2048;

  const _Float16* fa = ldsA + (wm * 64 + r) * 32 + quad * 8;
  const _Float16* fb = ldsB + (wn * 64 + r) * 32 + quad * 8;

  fv4 acc[4][4] = {};

  const int kiters = K >> 5;
  for (int kk = 0; kk < kiters; ++kk) {
    gload16(ap0,        dA0);
    gload16(ap0 + half, dA1);
    gload16(bp0,        dB0);
    gload16(bp0 + half, dB1);
    ap0 += 32; bp0 += 32;
    __syncthreads();

    hv8 av[4], bv[4];
#pragma unroll
    for (int t = 0; t < 4; ++t) {
      av[t] = *(const hv8*)(fa + t * 512);
      bv[t] = *(const hv8*)(fb + t * 512);
    }
#pragma unroll
    for (int tm = 0; tm < 4; ++tm) {
#pragma unroll
      for (int tn = 0; tn < 4; ++tn) {
        acc[tm][tn] = __builtin_amdgcn_mfma_f32_16x16x32_f16(av[tm], bv[tn],
                                                             acc[tm][tn], 0, 0, 0);
      }
    }
    __syncthreads();
  }

  const int col0 = n0 + wn * 64 + r;
  const int row0 = m0 + wm * 64 + quad * 4;
#pragma unroll
  for (int tn = 0; tn < 4; ++tn) {
    const int col = col0 + tn * 16;
    const float bs = bias[col];
#pragma unroll
    for (int tm = 0; tm < 4; ++tm) {
#pragma unroll
      for (int r2 = 0; r2 < 4; ++r2) {
        C[(size_t)(row0 + tm * 16 + r2) * N + col] = acc[tm][tn][r2] + bs;
      }
    }
  }
}

// ---------------------------------------------------------------------------
// elementwise fp32 -> f16
// ---------------------------------------------------------------------------
__global__ void cvt_f16(const float* __restrict__ x, _Float16* __restrict__ y) {
  size_t i = ((size_t)blockIdx.x * 256 + threadIdx.x) * 4;
  fv4 v = *(const fv4*)(x + i);
  *(hv4*)(y + i) = __builtin_convertvector(v, hv4);
}

// ---------------------------------------------------------------------------
// W[K,N] fp32 -> Wt f16 with per-32-col output row mapping:
// cols j = blockIdx.x*32 + i  ->  output rows blockIdx.x*mult + off + i.
// plain transpose: mult=32, off=0.  fused z: mult=64 off=0; fused h: mult=64 off=32.
// ---------------------------------------------------------------------------
__global__ void transpose_cvt(const float* __restrict__ W, _Float16* __restrict__ Wt,
                              int K, int N, int mult, int off) {
  __shared__ float tile[32][33];
  const int tx = threadIdx.x, ty = threadIdx.y;
  const int n  = blockIdx.x * 32 + tx;
  const int kb = blockIdx.y * 32;
  for (int i = ty; i < 32; i += 8)
    tile[i][tx] = W[(size_t)(kb + i) * N + n];
  __syncthreads();
  const int k = kb + tx;
  for (int i = ty; i < 32; i += 8)
    Wt[(size_t)(blockIdx.x * mult + off + i) * K + k] = (_Float16)tile[tx][i];
}

// ---------------------------------------------------------------------------
// chunked scan, T=4096 as 64 chunks of 64, per (b,j). a,b interleaved in zh2.
// phase A: per-chunk composition (Aa = prod a, Bv = chunk result from h_in=0)
// ---------------------------------------------------------------------------
__global__ void scan_phaseA(const _Float16* __restrict__ zh2,
                            float* __restrict__ cA, float* __restrict__ cB) {
  const int idx = blockIdx.x * 256 + threadIdx.x;  // B*64*(H/4) = 131072
  const int h  = (idx & 255) * 4;
  const int c  = (idx >> 8) & 63;
  const int bb = idx >> 14;
  const size_t base = ((size_t)(bb * 4096 + c * 64) * 1024 + h) * 2;
  fv4 Aa = {1.0f, 1.0f, 1.0f, 1.0f};
  fv4 Bv = {0.0f, 0.0f, 0.0f, 0.0f};
#pragma unroll 4
  for (int t = 0; t < 64; ++t) {
    hv8 v = *(const hv8*)(zh2 + base + (size_t)t * 2048);
    fv4 av = __builtin_convertvector(__builtin_shufflevector(v, v, 0, 2, 4, 6), fv4);
    fv4 bv = __builtin_convertvector(__builtin_shufflevector(v, v, 1, 3, 5, 7), fv4);
    Aa = Aa * av;
    Bv = av * Bv + bv;
  }
  const size_t o = (size_t)(bb * 64 + c) * 1024 + h;
  *(fv4*)(cA + o) = Aa;
  *(fv4*)(cB + o) = Bv;
}

// phase B: wave-parallel scan over the 64 chunks (lane = chunk), Hillis-Steele.
// hcy[c] = h entering chunk c (exclusive scan, h0 = 0).
__global__ void scan_phaseB(const float* __restrict__ cA, const float* __restrict__ cB,
                            float* __restrict__ hcy) {
  const int gtid = blockIdx.x * 256 + threadIdx.x;  // 2048 waves * 64
  const int lane = gtid & 63;                       // chunk id
  const int wid  = gtid >> 6;                       // (bb, h-group)
  const int h  = (wid & 255) * 4;
  const int bb = wid >> 8;
  const size_t o = (size_t)(bb * 64 + lane) * 1024 + h;
  fv4 Aa = *(const fv4*)(cA + o);
  fv4 Bv = *(const fv4*)(cB + o);
#pragma unroll
  for (int d = 1; d < 64; d <<= 1) {
    fv4 Ap, Bp;
#pragma unroll
    for (int k = 0; k < 4; ++k) {
      Ap[k] = __shfl_up(Aa[k], d, 64);
      Bp[k] = __shfl_up(Bv[k], d, 64);
    }
    if (lane >= d) {
      Bv = Aa * Bp + Bv;   // combine(prev, cur)
      Aa = Ap * Aa;
    }
  }
  fv4 hc;
#pragma unroll
  for (int k = 0; k < 4; ++k) hc[k] = __shfl_up(Bv[k], 1, 64);
  if (lane == 0) { hc.x = 0.f; hc.y = 0.f; hc.z = 0.f; hc.w = 0.f; }
  *(fv4*)(hcy + o) = hc;
}

// phase C: replay chunk with correct carry, emit h (f16, [M,1024])
__global__ void scan_phaseC(const _Float16* __restrict__ zh2,
                            const float* __restrict__ hcy,
                            _Float16* __restrict__ hout) {
  const int idx = blockIdx.x * 256 + threadIdx.x;
  const int h  = (idx & 255) * 4;
  const int c  = (idx >> 8) & 63;
  const int bb = idx >> 14;
  const size_t base = ((size_t)(bb * 4096 + c * 64) * 1024 + h) * 2;
  const size_t ob   = (size_t)(bb * 4096 + c * 64) * 1024 + h;
  const size_t o    = (size_t)(bb * 64 + c) * 1024 + h;
  fv4 hc = *(const fv4*)(hcy + o);
#pragma unroll 4
  for (int t = 0; t < 64; ++t) {
    hv8 v = *(const hv8*)(zh2 + base + (size_t)t * 2048);
    fv4 av = __builtin_convertvector(__builtin_shufflevector(v, v, 0, 2, 4, 6), fv4);
    fv4 bv = __builtin_convertvector(__builtin_shufflevector(v, v, 1, 3, 5, 7), fv4);
    hc = av * hc + bv;
    *(hv4*)(hout + ob + (size_t)t * 1024) = __builtin_convertvector(hc, hv4);
  }
}

// ---------------------------------------------------------------------------
extern "C" void kernel_launch(void* const* d_in, const int* in_sizes, int n_in,
                              void* d_out, int out_size, void* d_ws, size_t ws_size,
                              hipStream_t stream) {
  const float* x   = (const float*)d_in[0];
  const float* Wz0 = (const float*)d_in[1];
  const float* bz0 = (const float*)d_in[2];
  const float* Wh0 = (const float*)d_in[3];
  const float* bh0 = (const float*)d_in[4];
  const float* Wz1 = (const float*)d_in[5];
  const float* bz1 = (const float*)d_in[6];
  const float* Wh1 = (const float*)d_in[7];
  const float* bh1 = (const float*)d_in[8];
  const float* Wfc = (const float*)d_in[9];
  const float* bfc = (const float*)d_in[10];

  const int Mrows = 32768;  // B*T
  const int H = 1024, Din = 512, Dout = 512;

  // workspace layout (~205 MiB)
  char* w = (char*)d_ws;
  _Float16* zh2   = (_Float16*)w; w += (size_t)Mrows * 2 * H * 2;   // 128 MiB: (a,b) pairs
  _Float16* hx    = (_Float16*)w; w += (size_t)Mrows * H * 2;       //  64 MiB: Xb then h0/h1
  _Float16* Wzh0t = (_Float16*)w; w += (size_t)2 * H * Din * 2;     //   2 MiB
  _Float16* Wzh1t = (_Float16*)w; w += (size_t)2 * H * H * 2;       //   4 MiB
  _Float16* Wft   = (_Float16*)w; w += (size_t)Dout * H * 2;        //   1 MiB
  float*    cA    = (float*)w;    w += (size_t)8 * 64 * H * 4;      //   2 MiB
  float*    cB    = (float*)w;    w += (size_t)8 * 64 * H * 4;      //   2 MiB
  float*    hcy   = (float*)w;    w += (size_t)8 * 64 * H * 4;      //   2 MiB
  _Float16* Xb    = hx;  // aliased: x(f16) dead before h0 is written

  // --- input conversions (fused z|h row mapping for layer weights) ---
  cvt_f16<<<Mrows * Din / 1024, 256, 0, stream>>>(x, Xb);
  transpose_cvt<<<dim3(H / 32, Din / 32), dim3(32, 8), 0, stream>>>(Wz0, Wzh0t, Din, H, 64, 0);
  transpose_cvt<<<dim3(H / 32, Din / 32), dim3(32, 8), 0, stream>>>(Wh0, Wzh0t, Din, H, 64, 32);
  transpose_cvt<<<dim3(H / 32, H / 32),   dim3(32, 8), 0, stream>>>(Wz1, Wzh1t, H, H, 64, 0);
  transpose_cvt<<<dim3(H / 32, H / 32),   dim3(32, 8), 0, stream>>>(Wh1, Wzh1t, H, H, 64, 32);
  transpose_cvt<<<dim3(Dout / 32, H / 32), dim3(32, 8), 0, stream>>>(Wfc, Wft, H, Dout, 32, 0);

  const dim3 gG(2 * H / 128, Mrows / 128);   // fused z|h GEMM+gate, N=2048

  // --- layer 0 ---
  gemm_gate<<<gG, 256, 0, stream>>>(Xb, Wzh0t, zh2, bz0, bh0, Din);
  scan_phaseA<<<512, 256, 0, stream>>>(zh2, cA, cB);
  scan_phaseB<<<512, 256, 0, stream>>>(cA, cB, hcy);
  scan_phaseC<<<512, 256, 0, stream>>>(zh2, hcy, hx);

  // --- layer 1 ---
  gemm_gate<<<gG, 256, 0, stream>>>(hx, Wzh1t, zh2, bz1, bh1, H);
  scan_phaseA<<<512, 256, 0, stream>>>(zh2, cA, cB);
  scan_phaseB<<<512, 256, 0, stream>>>(cA, cB, hcy);
  scan_phaseC<<<512, 256, 0, stream>>>(zh2, hcy, hx);

  // --- FC head ---
  const dim3 gF(Dout / 128, Mrows / 128);
  gemm_f16_bt<<<gF, 256, 0, stream>>>(hx, Wft, (float*)d_out, bfc, Dout, H);
}

// Round 4
// 612.217 us; speedup vs baseline: 1.1435x; 1.0721x over previous
//
#include <hip/hip_runtime.h>

typedef __attribute__((ext_vector_type(4))) float fv4;
typedef __attribute__((ext_vector_type(8))) _Float16 hv8;
typedef __attribute__((ext_vector_type(4))) _Float16 hv4;
typedef __attribute__((ext_vector_type(2))) _Float16 hv2;

// ---------------------------------------------------------------------------
// async global->LDS 16B copy (wave-uniform LDS base + lane*16 semantics)
// ---------------------------------------------------------------------------
__device__ __forceinline__ void gload16(const void* g, void* l) {
  __builtin_amdgcn_global_load_lds(
      (const __attribute__((address_space(1))) unsigned int*)g,
      (__attribute__((address_space(3))) unsigned int*)l, 16, 0, 0);
}

// ---------------------------------------------------------------------------
// Shared K-loop: BK=64 as two physical BK=32 tiles (layouts identical to the
// proven BK=32 pattern; barriers per K halved). acc += A[128,K] @ Bt[128,K]^T
// ---------------------------------------------------------------------------
struct GemmCore {
  const _Float16 *ap0, *bp0;
  size_t half;
  _Float16 *ldsA0, *ldsA1, *ldsB0, *ldsB1;
  const _Float16 *fa0, *fa1, *fb0, *fb1;
  int wave;

  __device__ __forceinline__ void init(const _Float16* A, const _Float16* Bt,
                                       _Float16* lds, int m0, int n0, int K,
                                       int tid) {
    wave = tid >> 6;
    const int lane = tid & 63;
    const int wm = (wave >> 1), wn = (wave & 1);
    const int quad = lane >> 4, r = lane & 15;
    ldsA0 = lds;         ldsA1 = lds + 4096;
    ldsB0 = lds + 8192;  ldsB1 = lds + 12288;
    ap0 = A  + (size_t)(m0 + (tid >> 2)) * K + (tid & 3) * 8;
    bp0 = Bt + (size_t)(n0 + (tid >> 2)) * K + (tid & 3) * 8;
    half = (size_t)64 * K;
    fa0 = ldsA0 + (wm * 64 + r) * 32 + quad * 8;
    fa1 = ldsA1 + (wm * 64 + r) * 32 + quad * 8;
    fb0 = ldsB0 + (wn * 64 + r) * 32 + quad * 8;
    fb1 = ldsB1 + (wn * 64 + r) * 32 + quad * 8;
  }

  __device__ __forceinline__ void run(fv4 acc[4][4], int K) {
    const int kiters = K >> 6;
    for (int kk = 0; kk < kiters; ++kk) {
      gload16(ap0,             ldsA0 + wave * 512);
      gload16(ap0 + half,      ldsA0 + wave * 512 + 2048);
      gload16(ap0 + 32,        ldsA1 + wave * 512);
      gload16(ap0 + half + 32, ldsA1 + wave * 512 + 2048);
      gload16(bp0,             ldsB0 + wave * 512);
      gload16(bp0 + half,      ldsB0 + wave * 512 + 2048);
      gload16(bp0 + 32,        ldsB1 + wave * 512);
      gload16(bp0 + half + 32, ldsB1 + wave * 512 + 2048);
      ap0 += 64; bp0 += 64;
      __syncthreads();   // drains vmcnt -> all 4 tiles complete

      hv8 av[4], bv[4];
#pragma unroll
      for (int t = 0; t < 4; ++t) {
        av[t] = *(const hv8*)(fa0 + t * 512);
        bv[t] = *(const hv8*)(fb0 + t * 512);
      }
#pragma unroll
      for (int tm = 0; tm < 4; ++tm)
#pragma unroll
        for (int tn = 0; tn < 4; ++tn)
          acc[tm][tn] = __builtin_amdgcn_mfma_f32_16x16x32_f16(av[tm], bv[tn],
                                                               acc[tm][tn], 0, 0, 0);
#pragma unroll
      for (int t = 0; t < 4; ++t) {
        av[t] = *(const hv8*)(fa1 + t * 512);
        bv[t] = *(const hv8*)(fb1 + t * 512);
      }
#pragma unroll
      for (int tm = 0; tm < 4; ++tm)
#pragma unroll
        for (int tn = 0; tn < 4; ++tn)
          acc[tm][tn] = __builtin_amdgcn_mfma_f32_16x16x32_f16(av[tm], bv[tn],
                                                               acc[tm][tn], 0, 0, 0);
      __syncthreads();   // all reads done before next staging
    }
  }
};

// ---------------------------------------------------------------------------
// Fused layer GEMM + minGRU gate.
// Btf[2048,K] = fused z|h weight, rows [b*64,b*64+32) = Wz cols b*32..,
// [b*64+32,b*64+64) = Wh cols b*32...  Epilogue: a=1-sigmoid(zpre+bz),
// b=sigmoid(..)*(hpre+bh), stored interleaved (a,b) f16 pairs.
// ---------------------------------------------------------------------------
__global__ __launch_bounds__(256)
void gemm_gate(const _Float16* __restrict__ A, const _Float16* __restrict__ Btf,
               _Float16* __restrict__ zh2,
               const float* __restrict__ bz, const float* __restrict__ bh,
               int K) {
  __shared__ _Float16 lds[4 * 128 * 32];
  const int tid  = threadIdx.x;
  const int lane = tid & 63;
  const int wave = tid >> 6;
  const int wm = wave >> 1, wn = wave & 1;
  const int quad = lane >> 4, r = lane & 15;
  const int m0 = blockIdx.y * 128;
  const int n0 = blockIdx.x * 128;

  GemmCore core;
  core.init(A, Btf, lds, m0, n0, K, tid);
  fv4 acc[4][4] = {};
  core.run(acc, K);

  // C/D layout: col = lane&15, row = quad*4 + reg (m89-verified).
  // tn 0,1 = zpre for j = jb+tn*16+r; tn 2,3 = hpre for same j.
  const int jb   = (n0 + wn * 64) >> 1;
  const int row0 = m0 + wm * 64 + quad * 4;
#pragma unroll
  for (int tn = 0; tn < 2; ++tn) {
    const int j = jb + tn * 16 + r;
    const float bzv = bz[j];
    const float bhv = bh[j];
#pragma unroll
    for (int tm = 0; tm < 4; ++tm) {
#pragma unroll
      for (int r2 = 0; r2 < 4; ++r2) {
        const float zpre = acc[tm][tn][r2] + bzv;
        const float hpre = acc[tm][tn + 2][r2] + bhv;
        const float z = 1.0f / (1.0f + __expf(-zpre));
        hv2 ab = {(_Float16)(1.0f - z), (_Float16)(z * hpre)};
        *(hv2*)(zh2 + ((size_t)(row0 + tm * 16 + r2) * 1024 + j) * 2) = ab;
      }
    }
  }
}

// ---------------------------------------------------------------------------
// Plain GEMM (FC head): C[M,N] fp32 = A[M,K] f16 @ Bt[N,K]^T + bias
// ---------------------------------------------------------------------------
__global__ __launch_bounds__(256)
void gemm_f16_bt(const _Float16* __restrict__ A, const _Float16* __restrict__ Bt,
                 float* __restrict__ C, const float* __restrict__ bias,
                 int N, int K) {
  __shared__ _Float16 lds[4 * 128 * 32];
  const int tid  = threadIdx.x;
  const int lane = tid & 63;
  const int wave = tid >> 6;
  const int wm = wave >> 1, wn = wave & 1;
  const int quad = lane >> 4, r = lane & 15;
  const int m0 = blockIdx.y * 128;
  const int n0 = blockIdx.x * 128;

  GemmCore core;
  core.init(A, Bt, lds, m0, n0, K, tid);
  fv4 acc[4][4] = {};
  core.run(acc, K);

  const int col0 = n0 + wn * 64 + r;
  const int row0 = m0 + wm * 64 + quad * 4;
#pragma unroll
  for (int tn = 0; tn < 4; ++tn) {
    const int col = col0 + tn * 16;
    const float bs = bias[col];
#pragma unroll
    for (int tm = 0; tm < 4; ++tm) {
#pragma unroll
      for (int r2 = 0; r2 < 4; ++r2) {
        C[(size_t)(row0 + tm * 16 + r2) * N + col] = acc[tm][tn][r2] + bs;
      }
    }
  }
}

// ---------------------------------------------------------------------------
// elementwise fp32 -> f16
// ---------------------------------------------------------------------------
__global__ void cvt_f16(const float* __restrict__ x, _Float16* __restrict__ y) {
  size_t i = ((size_t)blockIdx.x * 256 + threadIdx.x) * 4;
  fv4 v = *(const fv4*)(x + i);
  *(hv4*)(y + i) = __builtin_convertvector(v, hv4);
}

// ---------------------------------------------------------------------------
// W[K,N] fp32 -> Wt f16; cols j = bx*32+i -> output rows bx*mult + off + i.
// ---------------------------------------------------------------------------
__global__ void transpose_cvt(const float* __restrict__ W, _Float16* __restrict__ Wt,
                              int K, int N, int mult, int off) {
  __shared__ float tile[32][33];
  const int tx = threadIdx.x, ty = threadIdx.y;
  const int n  = blockIdx.x * 32 + tx;
  const int kb = blockIdx.y * 32;
  for (int i = ty; i < 32; i += 8)
    tile[i][tx] = W[(size_t)(kb + i) * N + n];
  __syncthreads();
  const int k = kb + tx;
  for (int i = ty; i < 32; i += 8)
    Wt[(size_t)(blockIdx.x * mult + off + i) * K + k] = (_Float16)tile[tx][i];
}

// ---------------------------------------------------------------------------
// chunked scan, T=4096 as 64 chunks of 64, per (b,j). a,b interleaved in zh2.
// ---------------------------------------------------------------------------
__global__ void scan_phaseA(const _Float16* __restrict__ zh2,
                            float* __restrict__ cA, float* __restrict__ cB) {
  const int idx = blockIdx.x * 256 + threadIdx.x;  // B*64*(H/4) = 131072
  const int h  = (idx & 255) * 4;
  const int c  = (idx >> 8) & 63;
  const int bb = idx >> 14;
  const size_t base = ((size_t)(bb * 4096 + c * 64) * 1024 + h) * 2;
  fv4 Aa = {1.0f, 1.0f, 1.0f, 1.0f};
  fv4 Bv = {0.0f, 0.0f, 0.0f, 0.0f};
#pragma unroll 4
  for (int t = 0; t < 64; ++t) {
    hv8 v = *(const hv8*)(zh2 + base + (size_t)t * 2048);
    fv4 av = __builtin_convertvector(__builtin_shufflevector(v, v, 0, 2, 4, 6), fv4);
    fv4 bv = __builtin_convertvector(__builtin_shufflevector(v, v, 1, 3, 5, 7), fv4);
    Aa = Aa * av;
    Bv = av * Bv + bv;
  }
  const size_t o = (size_t)(bb * 64 + c) * 1024 + h;
  *(fv4*)(cA + o) = Aa;
  *(fv4*)(cB + o) = Bv;
}

// phase B: wave-parallel Hillis-Steele over chunks (lane = chunk).
__global__ void scan_phaseB(const float* __restrict__ cA, const float* __restrict__ cB,
                            float* __restrict__ hcy) {
  const int gtid = blockIdx.x * 256 + threadIdx.x;  // 2048 waves * 64
  const int lane = gtid & 63;
  const int wid  = gtid >> 6;
  const int h  = (wid & 255) * 4;
  const int bb = wid >> 8;
  const size_t o = (size_t)(bb * 64 + lane) * 1024 + h;
  fv4 Aa = *(const fv4*)(cA + o);
  fv4 Bv = *(const fv4*)(cB + o);
#pragma unroll
  for (int d = 1; d < 64; d <<= 1) {
    fv4 Ap, Bp;
#pragma unroll
    for (int k = 0; k < 4; ++k) {
      Ap[k] = __shfl_up(Aa[k], d, 64);
      Bp[k] = __shfl_up(Bv[k], d, 64);
    }
    if (lane >= d) {
      Bv = Aa * Bp + Bv;
      Aa = Ap * Aa;
    }
  }
  fv4 hc;
#pragma unroll
  for (int k = 0; k < 4; ++k) hc[k] = __shfl_up(Bv[k], 1, 64);
  if (lane == 0) { hc.x = 0.f; hc.y = 0.f; hc.z = 0.f; hc.w = 0.f; }
  *(fv4*)(hcy + o) = hc;
}

// phase C: replay chunk with correct carry, emit h (f16, [M,1024])
__global__ void scan_phaseC(const _Float16* __restrict__ zh2,
                            const float* __restrict__ hcy,
                            _Float16* __restrict__ hout) {
  const int idx = blockIdx.x * 256 + threadIdx.x;
  const int h  = (idx & 255) * 4;
  const int c  = (idx >> 8) & 63;
  const int bb = idx >> 14;
  const size_t base = ((size_t)(bb * 4096 + c * 64) * 1024 + h) * 2;
  const size_t ob   = (size_t)(bb * 4096 + c * 64) * 1024 + h;
  const size_t o    = (size_t)(bb * 64 + c) * 1024 + h;
  fv4 hc = *(const fv4*)(hcy + o);
#pragma unroll 4
  for (int t = 0; t < 64; ++t) {
    hv8 v = *(const hv8*)(zh2 + base + (size_t)t * 2048);
    fv4 av = __builtin_convertvector(__builtin_shufflevector(v, v, 0, 2, 4, 6), fv4);
    fv4 bv = __builtin_convertvector(__builtin_shufflevector(v, v, 1, 3, 5, 7), fv4);
    hc = av * hc + bv;
    *(hv4*)(hout + ob + (size_t)t * 1024) = __builtin_convertvector(hc, hv4);
  }
}

// ---------------------------------------------------------------------------
extern "C" void kernel_launch(void* const* d_in, const int* in_sizes, int n_in,
                              void* d_out, int out_size, void* d_ws, size_t ws_size,
                              hipStream_t stream) {
  const float* x   = (const float*)d_in[0];
  const float* Wz0 = (const float*)d_in[1];
  const float* bz0 = (const float*)d_in[2];
  const float* Wh0 = (const float*)d_in[3];
  const float* bh0 = (const float*)d_in[4];
  const float* Wz1 = (const float*)d_in[5];
  const float* bz1 = (const float*)d_in[6];
  const float* Wh1 = (const float*)d_in[7];
  const float* bh1 = (const float*)d_in[8];
  const float* Wfc = (const float*)d_in[9];
  const float* bfc = (const float*)d_in[10];

  const int Mrows = 32768;  // B*T
  const int H = 1024, Din = 512, Dout = 512;

  // workspace layout (~205 MiB)
  char* w = (char*)d_ws;
  _Float16* zh2   = (_Float16*)w; w += (size_t)Mrows * 2 * H * 2;   // 128 MiB
  _Float16* hx    = (_Float16*)w; w += (size_t)Mrows * H * 2;       //  64 MiB
  _Float16* Wzh0t = (_Float16*)w; w += (size_t)2 * H * Din * 2;
  _Float16* Wzh1t = (_Float16*)w; w += (size_t)2 * H * H * 2;
  _Float16* Wft   = (_Float16*)w; w += (size_t)Dout * H * 2;
  float*    cA    = (float*)w;    w += (size_t)8 * 64 * H * 4;
  float*    cB    = (float*)w;    w += (size_t)8 * 64 * H * 4;
  float*    hcy   = (float*)w;    w += (size_t)8 * 64 * H * 4;
  _Float16* Xb    = hx;  // aliased: x(f16) dead before h0 is written

  // --- input conversions (fused z|h row mapping for layer weights) ---
  cvt_f16<<<Mrows * Din / 1024, 256, 0, stream>>>(x, Xb);
  transpose_cvt<<<dim3(H / 32, Din / 32), dim3(32, 8), 0, stream>>>(Wz0, Wzh0t, Din, H, 64, 0);
  transpose_cvt<<<dim3(H / 32, Din / 32), dim3(32, 8), 0, stream>>>(Wh0, Wzh0t, Din, H, 64, 32);
  transpose_cvt<<<dim3(H / 32, H / 32),   dim3(32, 8), 0, stream>>>(Wz1, Wzh1t, H, H, 64, 0);
  transpose_cvt<<<dim3(H / 32, H / 32),   dim3(32, 8), 0, stream>>>(Wh1, Wzh1t, H, H, 64, 32);
  transpose_cvt<<<dim3(Dout / 32, H / 32), dim3(32, 8), 0, stream>>>(Wfc, Wft, H, Dout, 32, 0);

  const dim3 gG(2 * H / 128, Mrows / 128);   // fused z|h GEMM+gate, N=2048

  // --- layer 0 ---
  gemm_gate<<<gG, 256, 0, stream>>>(Xb, Wzh0t, zh2, bz0, bh0, Din);
  scan_phaseA<<<512, 256, 0, stream>>>(zh2, cA, cB);
  scan_phaseB<<<512, 256, 0, stream>>>(cA, cB, hcy);
  scan_phaseC<<<512, 256, 0, stream>>>(zh2, hcy, hx);

  // --- layer 1 ---
  gemm_gate<<<gG, 256, 0, stream>>>(hx, Wzh1t, zh2, bz1, bh1, H);
  scan_phaseA<<<512, 256, 0, stream>>>(zh2, cA, cB);
  scan_phaseB<<<512, 256, 0, stream>>>(cA, cB, hcy);
  scan_phaseC<<<512, 256, 0, stream>>>(zh2, hcy, hx);

  // --- FC head ---
  const dim3 gF(Dout / 128, Mrows / 128);
  gemm_f16_bt<<<gF, 256, 0, stream>>>(hx, Wft, (float*)d_out, bfc, Dout, H);
}

// Round 5
// 598.164 us; speedup vs baseline: 1.1703x; 1.0235x over previous
//
#include <hip/hip_runtime.h>

typedef __attribute__((ext_vector_type(4))) float fv4;
typedef __attribute__((ext_vector_type(8))) _Float16 hv8;
typedef __attribute__((ext_vector_type(4))) _Float16 hv4;
typedef __attribute__((ext_vector_type(2))) _Float16 hv2;

// ---------------------------------------------------------------------------
// async global->LDS 16B copy (wave-uniform LDS base + lane*16 semantics)
// ---------------------------------------------------------------------------
__device__ __forceinline__ void gload16(const void* g, void* l) {
  __builtin_amdgcn_global_load_lds(
      (const __attribute__((address_space(1))) unsigned int*)g,
      (__attribute__((address_space(3))) unsigned int*)l, 16, 0, 0);
}

// ---------------------------------------------------------------------------
// Shared K-loop: BK=64 as two physical BK=32 tiles; barriers per K halved.
// Bank-conflict fix: column-group XOR swizzle. Physical LDS slot (row, cg)
// holds logical column-group cg ^ ((row>>1)&3); fragment reads use
// quad ^ ((r>>1)&3). Bankgroup = 4*(r&1) + swizzled-cg -> 2-way max (free).
// ---------------------------------------------------------------------------
struct GemmCore {
  const _Float16 *ap0, *bp0;
  size_t half;
  _Float16 *ldsA0, *ldsA1, *ldsB0, *ldsB1;
  const _Float16 *fa0, *fa1, *fb0, *fb1;
  int wave;

  __device__ __forceinline__ void init(const _Float16* A, const _Float16* Bt,
                                       _Float16* lds, int m0, int n0, int K,
                                       int tid) {
    wave = tid >> 6;
    const int lane = tid & 63;
    const int wm = (wave >> 1), wn = (wave & 1);
    const int quad = lane >> 4, r = lane & 15;
    ldsA0 = lds;         ldsA1 = lds + 4096;
    ldsB0 = lds + 8192;  ldsB1 = lds + 12288;
    // staging: physical slot row = tid>>2, cg = tid&3 loads logical
    // column-group cg ^ ((row>>1)&3)  (row+64 preserves (row>>1)&3)
    const int cg = (tid & 3) ^ ((tid >> 3) & 3);
    ap0 = A  + (size_t)(m0 + (tid >> 2)) * K + cg * 8;
    bp0 = Bt + (size_t)(n0 + (tid >> 2)) * K + cg * 8;
    half = (size_t)64 * K;
    // fragment reads: logical (row = ..+r, quad) lives at swizzled cg
    const int sq = quad ^ ((r >> 1) & 3);
    fa0 = ldsA0 + (wm * 64 + r) * 32 + sq * 8;
    fa1 = ldsA1 + (wm * 64 + r) * 32 + sq * 8;
    fb0 = ldsB0 + (wn * 64 + r) * 32 + sq * 8;
    fb1 = ldsB1 + (wn * 64 + r) * 32 + sq * 8;
  }

  __device__ __forceinline__ void run(fv4 acc[4][4], int K) {
    const int kiters = K >> 6;
    for (int kk = 0; kk < kiters; ++kk) {
      gload16(ap0,             ldsA0 + wave * 512);
      gload16(ap0 + half,      ldsA0 + wave * 512 + 2048);
      gload16(ap0 + 32,        ldsA1 + wave * 512);
      gload16(ap0 + half + 32, ldsA1 + wave * 512 + 2048);
      gload16(bp0,             ldsB0 + wave * 512);
      gload16(bp0 + half,      ldsB0 + wave * 512 + 2048);
      gload16(bp0 + 32,        ldsB1 + wave * 512);
      gload16(bp0 + half + 32, ldsB1 + wave * 512 + 2048);
      ap0 += 64; bp0 += 64;
      __syncthreads();   // drains vmcnt -> all 4 tiles complete

      hv8 av[4], bv[4];
#pragma unroll
      for (int t = 0; t < 4; ++t) {
        av[t] = *(const hv8*)(fa0 + t * 512);
        bv[t] = *(const hv8*)(fb0 + t * 512);
      }
#pragma unroll
      for (int tm = 0; tm < 4; ++tm)
#pragma unroll
        for (int tn = 0; tn < 4; ++tn)
          acc[tm][tn] = __builtin_amdgcn_mfma_f32_16x16x32_f16(av[tm], bv[tn],
                                                               acc[tm][tn], 0, 0, 0);
#pragma unroll
      for (int t = 0; t < 4; ++t) {
        av[t] = *(const hv8*)(fa1 + t * 512);
        bv[t] = *(const hv8*)(fb1 + t * 512);
      }
#pragma unroll
      for (int tm = 0; tm < 4; ++tm)
#pragma unroll
        for (int tn = 0; tn < 4; ++tn)
          acc[tm][tn] = __builtin_amdgcn_mfma_f32_16x16x32_f16(av[tm], bv[tn],
                                                               acc[tm][tn], 0, 0, 0);
      __syncthreads();   // all reads done before next staging
    }
  }
};

// ---------------------------------------------------------------------------
// Fused layer GEMM + minGRU gate.
// Btf[2048,K] = fused z|h weight, rows [b*64,b*64+32) = Wz cols b*32..,
// [b*64+32,b*64+64) = Wh cols b*32...  Epilogue: a=1-sigmoid(zpre+bz),
// b=sigmoid(..)*(hpre+bh), stored interleaved (a,b) f16 pairs.
// ---------------------------------------------------------------------------
__global__ __launch_bounds__(256)
void gemm_gate(const _Float16* __restrict__ A, const _Float16* __restrict__ Btf,
               _Float16* __restrict__ zh2,
               const float* __restrict__ bz, const float* __restrict__ bh,
               int K) {
  __shared__ _Float16 lds[4 * 128 * 32];
  const int tid  = threadIdx.x;
  const int lane = tid & 63;
  const int wave = tid >> 6;
  const int wm = wave >> 1, wn = wave & 1;
  const int quad = lane >> 4, r = lane & 15;
  const int m0 = blockIdx.y * 128;
  const int n0 = blockIdx.x * 128;

  GemmCore core;
  core.init(A, Btf, lds, m0, n0, K, tid);
  fv4 acc[4][4] = {};
  core.run(acc, K);

  // C/D layout: col = lane&15, row = quad*4 + reg (m89-verified).
  // tn 0,1 = zpre for j = jb+tn*16+r; tn 2,3 = hpre for same j.
  const int jb   = (n0 + wn * 64) >> 1;
  const int row0 = m0 + wm * 64 + quad * 4;
#pragma unroll
  for (int tn = 0; tn < 2; ++tn) {
    const int j = jb + tn * 16 + r;
    const float bzv = bz[j];
    const float bhv = bh[j];
#pragma unroll
    for (int tm = 0; tm < 4; ++tm) {
#pragma unroll
      for (int r2 = 0; r2 < 4; ++r2) {
        const float zpre = acc[tm][tn][r2] + bzv;
        const float hpre = acc[tm][tn + 2][r2] + bhv;
        const float z = 1.0f / (1.0f + __expf(-zpre));
        hv2 ab = {(_Float16)(1.0f - z), (_Float16)(z * hpre)};
        *(hv2*)(zh2 + ((size_t)(row0 + tm * 16 + r2) * 1024 + j) * 2) = ab;
      }
    }
  }
}

// ---------------------------------------------------------------------------
// Plain GEMM (FC head): C[M,N] fp32 = A[M,K] f16 @ Bt[N,K]^T + bias
// ---------------------------------------------------------------------------
__global__ __launch_bounds__(256)
void gemm_f16_bt(const _Float16* __restrict__ A, const _Float16* __restrict__ Bt,
                 float* __restrict__ C, const float* __restrict__ bias,
                 int N, int K) {
  __shared__ _Float16 lds[4 * 128 * 32];
  const int tid  = threadIdx.x;
  const int lane = tid & 63;
  const int wave = tid >> 6;
  const int wm = wave >> 1, wn = wave & 1;
  const int quad = lane >> 4, r = lane & 15;
  const int m0 = blockIdx.y * 128;
  const int n0 = blockIdx.x * 128;

  GemmCore core;
  core.init(A, Bt, lds, m0, n0, K, tid);
  fv4 acc[4][4] = {};
  core.run(acc, K);

  const int col0 = n0 + wn * 64 + r;
  const int row0 = m0 + wm * 64 + quad * 4;
#pragma unroll
  for (int tn = 0; tn < 4; ++tn) {
    const int col = col0 + tn * 16;
    const float bs = bias[col];
#pragma unroll
    for (int tm = 0; tm < 4; ++tm) {
#pragma unroll
      for (int r2 = 0; r2 < 4; ++r2) {
        C[(size_t)(row0 + tm * 16 + r2) * N + col] = acc[tm][tn][r2] + bs;
      }
    }
  }
}

// ---------------------------------------------------------------------------
// elementwise fp32 -> f16
// ---------------------------------------------------------------------------
__global__ void cvt_f16(const float* __restrict__ x, _Float16* __restrict__ y) {
  size_t i = ((size_t)blockIdx.x * 256 + threadIdx.x) * 4;
  fv4 v = *(const fv4*)(x + i);
  *(hv4*)(y + i) = __builtin_convertvector(v, hv4);
}

// ---------------------------------------------------------------------------
// W[K,N] fp32 -> Wt f16; cols j = bx*32+i -> output rows bx*mult + off + i.
// ---------------------------------------------------------------------------
__global__ void transpose_cvt(const float* __restrict__ W, _Float16* __restrict__ Wt,
                              int K, int N, int mult, int off) {
  __shared__ float tile[32][33];
  const int tx = threadIdx.x, ty = threadIdx.y;
  const int n  = blockIdx.x * 32 + tx;
  const int kb = blockIdx.y * 32;
  for (int i = ty; i < 32; i += 8)
    tile[i][tx] = W[(size_t)(kb + i) * N + n];
  __syncthreads();
  const int k = kb + tx;
  for (int i = ty; i < 32; i += 8)
    Wt[(size_t)(blockIdx.x * mult + off + i) * K + k] = (_Float16)tile[tx][i];
}

// ---------------------------------------------------------------------------
// chunked scan, T=4096 as 64 chunks of 64, per (b,j). a,b interleaved in zh2.
// ---------------------------------------------------------------------------
__global__ void scan_phaseA(const _Float16* __restrict__ zh2,
                            float* __restrict__ cA, float* __restrict__ cB) {
  const int idx = blockIdx.x * 256 + threadIdx.x;  // B*64*(H/4) = 131072
  const int h  = (idx & 255) * 4;
  const int c  = (idx >> 8) & 63;
  const int bb = idx >> 14;
  const size_t base = ((size_t)(bb * 4096 + c * 64) * 1024 + h) * 2;
  fv4 Aa = {1.0f, 1.0f, 1.0f, 1.0f};
  fv4 Bv = {0.0f, 0.0f, 0.0f, 0.0f};
#pragma unroll 4
  for (int t = 0; t < 64; ++t) {
    hv8 v = *(const hv8*)(zh2 + base + (size_t)t * 2048);
    fv4 av = __builtin_convertvector(__builtin_shufflevector(v, v, 0, 2, 4, 6), fv4);
    fv4 bv = __builtin_convertvector(__builtin_shufflevector(v, v, 1, 3, 5, 7), fv4);
    Aa = Aa * av;
    Bv = av * Bv + bv;
  }
  const size_t o = (size_t)(bb * 64 + c) * 1024 + h;
  *(fv4*)(cA + o) = Aa;
  *(fv4*)(cB + o) = Bv;
}

// phase B: wave-parallel Hillis-Steele over chunks (lane = chunk).
__global__ void scan_phaseB(const float* __restrict__ cA, const float* __restrict__ cB,
                            float* __restrict__ hcy) {
  const int gtid = blockIdx.x * 256 + threadIdx.x;  // 2048 waves * 64
  const int lane = gtid & 63;
  const int wid  = gtid >> 6;
  const int h  = (wid & 255) * 4;
  const int bb = wid >> 8;
  const size_t o = (size_t)(bb * 64 + lane) * 1024 + h;
  fv4 Aa = *(const fv4*)(cA + o);
  fv4 Bv = *(const fv4*)(cB + o);
#pragma unroll
  for (int d = 1; d < 64; d <<= 1) {
    fv4 Ap, Bp;
#pragma unroll
    for (int k = 0; k < 4; ++k) {
      Ap[k] = __shfl_up(Aa[k], d, 64);
      Bp[k] = __shfl_up(Bv[k], d, 64);
    }
    if (lane >= d) {
      Bv = Aa * Bp + Bv;
      Aa = Ap * Aa;
    }
  }
  fv4 hc;
#pragma unroll
  for (int k = 0; k < 4; ++k) hc[k] = __shfl_up(Bv[k], 1, 64);
  if (lane == 0) { hc.x = 0.f; hc.y = 0.f; hc.z = 0.f; hc.w = 0.f; }
  *(fv4*)(hcy + o) = hc;
}

// phase C: replay chunk with correct carry, emit h (f16, [M,1024])
__global__ void scan_phaseC(const _Float16* __restrict__ zh2,
                            const float* __restrict__ hcy,
                            _Float16* __restrict__ hout) {
  const int idx = blockIdx.x * 256 + threadIdx.x;
  const int h  = (idx & 255) * 4;
  const int c  = (idx >> 8) & 63;
  const int bb = idx >> 14;
  const size_t base = ((size_t)(bb * 4096 + c * 64) * 1024 + h) * 2;
  const size_t ob   = (size_t)(bb * 4096 + c * 64) * 1024 + h;
  const size_t o    = (size_t)(bb * 64 + c) * 1024 + h;
  fv4 hc = *(const fv4*)(hcy + o);
#pragma unroll 4
  for (int t = 0; t < 64; ++t) {
    hv8 v = *(const hv8*)(zh2 + base + (size_t)t * 2048);
    fv4 av = __builtin_convertvector(__builtin_shufflevector(v, v, 0, 2, 4, 6), fv4);
    fv4 bv = __builtin_convertvector(__builtin_shufflevector(v, v, 1, 3, 5, 7), fv4);
    hc = av * hc + bv;
    *(hv4*)(hout + ob + (size_t)t * 1024) = __builtin_convertvector(hc, hv4);
  }
}

// ---------------------------------------------------------------------------
extern "C" void kernel_launch(void* const* d_in, const int* in_sizes, int n_in,
                              void* d_out, int out_size, void* d_ws, size_t ws_size,
                              hipStream_t stream) {
  const float* x   = (const float*)d_in[0];
  const float* Wz0 = (const float*)d_in[1];
  const float* bz0 = (const float*)d_in[2];
  const float* Wh0 = (const float*)d_in[3];
  const float* bh0 = (const float*)d_in[4];
  const float* Wz1 = (const float*)d_in[5];
  const float* bz1 = (const float*)d_in[6];
  const float* Wh1 = (const float*)d_in[7];
  const float* bh1 = (const float*)d_in[8];
  const float* Wfc = (const float*)d_in[9];
  const float* bfc = (const float*)d_in[10];

  const int Mrows = 32768;  // B*T
  const int H = 1024, Din = 512, Dout = 512;

  // workspace layout (~205 MiB)
  char* w = (char*)d_ws;
  _Float16* zh2   = (_Float16*)w; w += (size_t)Mrows * 2 * H * 2;   // 128 MiB
  _Float16* hx    = (_Float16*)w; w += (size_t)Mrows * H * 2;       //  64 MiB
  _Float16* Wzh0t = (_Float16*)w; w += (size_t)2 * H * Din * 2;
  _Float16* Wzh1t = (_Float16*)w; w += (size_t)2 * H * H * 2;
  _Float16* Wft   = (_Float16*)w; w += (size_t)Dout * H * 2;
  float*    cA    = (float*)w;    w += (size_t)8 * 64 * H * 4;
  float*    cB    = (float*)w;    w += (size_t)8 * 64 * H * 4;
  float*    hcy   = (float*)w;    w += (size_t)8 * 64 * H * 4;
  _Float16* Xb    = hx;  // aliased: x(f16) dead before h0 is written

  // --- input conversions (fused z|h row mapping for layer weights) ---
  cvt_f16<<<Mrows * Din / 1024, 256, 0, stream>>>(x, Xb);
  transpose_cvt<<<dim3(H / 32, Din / 32), dim3(32, 8), 0, stream>>>(Wz0, Wzh0t, Din, H, 64, 0);
  transpose_cvt<<<dim3(H / 32, Din / 32), dim3(32, 8), 0, stream>>>(Wh0, Wzh0t, Din, H, 64, 32);
  transpose_cvt<<<dim3(H / 32, H / 32),   dim3(32, 8), 0, stream>>>(Wz1, Wzh1t, H, H, 64, 0);
  transpose_cvt<<<dim3(H / 32, H / 32),   dim3(32, 8), 0, stream>>>(Wh1, Wzh1t, H, H, 64, 32);
  transpose_cvt<<<dim3(Dout / 32, H / 32), dim3(32, 8), 0, stream>>>(Wfc, Wft, H, Dout, 32, 0);

  const dim3 gG(2 * H / 128, Mrows / 128);   // fused z|h GEMM+gate, N=2048

  // --- layer 0 ---
  gemm_gate<<<gG, 256, 0, stream>>>(Xb, Wzh0t, zh2, bz0, bh0, Din);
  scan_phaseA<<<512, 256, 0, stream>>>(zh2, cA, cB);
  scan_phaseB<<<512, 256, 0, stream>>>(cA, cB, hcy);
  scan_phaseC<<<512, 256, 0, stream>>>(zh2, hcy, hx);

  // --- layer 1 ---
  gemm_gate<<<gG, 256, 0, stream>>>(hx, Wzh1t, zh2, bz1, bh1, H);
  scan_phaseA<<<512, 256, 0, stream>>>(zh2, cA, cB);
  scan_phaseB<<<512, 256, 0, stream>>>(cA, cB, hcy);
  scan_phaseC<<<512, 256, 0, stream>>>(zh2, hcy, hx);

  // --- FC head ---
  const dim3 gF(Dout / 128, Mrows / 128);
  gemm_f16_bt<<<gF, 256, 0, stream>>>(hx, Wft, (float*)d_out, bfc, Dout, H);
}

// Round 6
// 558.016 us; speedup vs baseline: 1.2545x; 1.0719x over previous
//
#include <hip/hip_runtime.h>

typedef __attribute__((ext_vector_type(4))) float fv4;
typedef __attribute__((ext_vector_type(8))) _Float16 hv8;
typedef __attribute__((ext_vector_type(4))) _Float16 hv4;
typedef __attribute__((ext_vector_type(2))) _Float16 hv2;

// ---------------------------------------------------------------------------
// async global->LDS 16B copy (wave-uniform LDS base + lane*16 semantics)
// ---------------------------------------------------------------------------
__device__ __forceinline__ void gload16(const void* g, void* l) {
  __builtin_amdgcn_global_load_lds(
      (const __attribute__((address_space(1))) unsigned int*)g,
      (__attribute__((address_space(3))) unsigned int*)l, 16, 0, 0);
}

// ---------------------------------------------------------------------------
// Shared K-loop: BK=64 as two physical BK=32 tiles; barriers per K halved.
// LDS XOR swizzle (R5): bank conflicts measured 0.
// ---------------------------------------------------------------------------
struct GemmCore {
  const _Float16 *ap0, *bp0;
  size_t half;
  _Float16 *ldsA0, *ldsA1, *ldsB0, *ldsB1;
  const _Float16 *fa0, *fa1, *fb0, *fb1;
  int wave;

  __device__ __forceinline__ void init(const _Float16* A, const _Float16* Bt,
                                       _Float16* lds, int m0, int n0, int K,
                                       int tid) {
    wave = tid >> 6;
    const int lane = tid & 63;
    const int wm = (wave >> 1), wn = (wave & 1);
    const int quad = lane >> 4, r = lane & 15;
    ldsA0 = lds;         ldsA1 = lds + 4096;
    ldsB0 = lds + 8192;  ldsB1 = lds + 12288;
    const int cg = (tid & 3) ^ ((tid >> 3) & 3);   // staged-side XOR swizzle
    ap0 = A  + (size_t)(m0 + (tid >> 2)) * K + cg * 8;
    bp0 = Bt + (size_t)(n0 + (tid >> 2)) * K + cg * 8;
    half = (size_t)64 * K;
    const int sq = quad ^ ((r >> 1) & 3);          // fragment-side swizzle
    fa0 = ldsA0 + (wm * 64 + r) * 32 + sq * 8;
    fa1 = ldsA1 + (wm * 64 + r) * 32 + sq * 8;
    fb0 = ldsB0 + (wn * 64 + r) * 32 + sq * 8;
    fb1 = ldsB1 + (wn * 64 + r) * 32 + sq * 8;
  }

  __device__ __forceinline__ void run(fv4 acc[4][4], int K) {
    const int kiters = K >> 6;
    for (int kk = 0; kk < kiters; ++kk) {
      gload16(ap0,             ldsA0 + wave * 512);
      gload16(ap0 + half,      ldsA0 + wave * 512 + 2048);
      gload16(ap0 + 32,        ldsA1 + wave * 512);
      gload16(ap0 + half + 32, ldsA1 + wave * 512 + 2048);
      gload16(bp0,             ldsB0 + wave * 512);
      gload16(bp0 + half,      ldsB0 + wave * 512 + 2048);
      gload16(bp0 + 32,        ldsB1 + wave * 512);
      gload16(bp0 + half + 32, ldsB1 + wave * 512 + 2048);
      ap0 += 64; bp0 += 64;
      __syncthreads();   // drains vmcnt -> all 4 tiles complete

      hv8 av[4], bv[4];
#pragma unroll
      for (int t = 0; t < 4; ++t) {
        av[t] = *(const hv8*)(fa0 + t * 512);
        bv[t] = *(const hv8*)(fb0 + t * 512);
      }
#pragma unroll
      for (int tm = 0; tm < 4; ++tm)
#pragma unroll
        for (int tn = 0; tn < 4; ++tn)
          acc[tm][tn] = __builtin_amdgcn_mfma_f32_16x16x32_f16(av[tm], bv[tn],
                                                               acc[tm][tn], 0, 0, 0);
#pragma unroll
      for (int t = 0; t < 4; ++t) {
        av[t] = *(const hv8*)(fa1 + t * 512);
        bv[t] = *(const hv8*)(fb1 + t * 512);
      }
#pragma unroll
      for (int tm = 0; tm < 4; ++tm)
#pragma unroll
        for (int tn = 0; tn < 4; ++tn)
          acc[tm][tn] = __builtin_amdgcn_mfma_f32_16x16x32_f16(av[tm], bv[tn],
                                                               acc[tm][tn], 0, 0, 0);
      __syncthreads();   // all reads done before next staging
    }
  }
};

// XCD-colocation block swizzle: blocks sharing one A-strip (all ntiles of one
// mtile) get linear ids congruent mod 8 -> same XCD -> A-strip hits in its L2.
__device__ __forceinline__ void xcd_map(int bid, int ntl2, int mt_per_x,
                                        int& m0, int& n0) {
  const int xcd = bid & 7;
  const int k2  = bid >> 3;
  m0 = (xcd * mt_per_x + (k2 >> ntl2)) * 128;
  n0 = (k2 & ((1 << ntl2) - 1)) * 128;
}

// ---------------------------------------------------------------------------
// Fused layer GEMM + minGRU gate + scan phase A.
// Btf[2048,K] = fused z|h weight (rows [b*64,b*64+32)=Wz cols, +32=Wh cols).
// Epilogue: a=1-sigmoid(zpre+bz), b=sigmoid(..)*(hpre+bh) stored interleaved
// (a,b) f16; then per-chunk (64 rows = wm-half of block) ordered composition
// (cA=prod a, cB=fold) computed in-register/shuffle and written by quad-3
// lanes. Composition uses the f16-rounded a,b in f32, same order as the old
// scan_phaseA -> bit-identical cA/cB.
// ---------------------------------------------------------------------------
__global__ __launch_bounds__(256)
void gemm_gate(const _Float16* __restrict__ A, const _Float16* __restrict__ Btf,
               _Float16* __restrict__ zh2,
               float* __restrict__ cA, float* __restrict__ cB,
               const float* __restrict__ bz, const float* __restrict__ bh,
               int K, int ntl2, int mt_per_x) {
  __shared__ _Float16 lds[4 * 128 * 32];
  const int tid  = threadIdx.x;
  const int lane = tid & 63;
  const int wave = tid >> 6;
  const int wm = wave >> 1, wn = wave & 1;
  const int quad = lane >> 4, r = lane & 15;
  int m0, n0;
  xcd_map(blockIdx.x, ntl2, mt_per_x, m0, n0);

  GemmCore core;
  core.init(A, Btf, lds, m0, n0, K, tid);
  fv4 acc[4][4] = {};
  core.run(acc, K);

  // C/D layout: col = lane&15, row = quad*4 + reg (m89-verified).
  // tn 0,1 = zpre for j = jb+tn*16+r; tn 2,3 = hpre for same j.
  // chunk-local t = 16*tm + 4*quad + r2 (covers [0,64) of this wm-half).
  const int jb   = (n0 + wn * 64) >> 1;
  const int row0 = m0 + wm * 64 + quad * 4;
  const int cidx = (m0 >> 6) + wm;   // global chunk index = row/64
#pragma unroll
  for (int tn = 0; tn < 2; ++tn) {
    const int j = jb + tn * 16 + r;
    const float bzv = bz[j];
    const float bhv = bh[j];
    float qA[4], qB[4];
#pragma unroll
    for (int tm = 0; tm < 4; ++tm) {
      float sA = 1.0f, sB = 0.0f;
#pragma unroll
      for (int r2 = 0; r2 < 4; ++r2) {
        const float zpre = acc[tm][tn][r2] + bzv;
        const float hpre = acc[tm][tn + 2][r2] + bhv;
        const float z = 1.0f / (1.0f + __expf(-zpre));
        const _Float16 a16 = (_Float16)(1.0f - z);
        const _Float16 b16 = (_Float16)(z * hpre);
        hv2 ab = {a16, b16};
        *(hv2*)(zh2 + ((size_t)(row0 + tm * 16 + r2) * 1024 + j) * 2) = ab;
        const float af = (float)a16, bf = (float)b16;
        sB = af * sB + bf;   // ordered fold, r2 ascending
        sA = sA * af;
      }
      qA[tm] = sA; qB[tm] = sB;
    }
    // inclusive scan across quads (rows 16tm+4q+r2; quad ascending)
#pragma unroll
    for (int tm = 0; tm < 4; ++tm) {
      float Av = qA[tm], Bv = qB[tm];
      float Ap = __shfl_up(Av, 16, 64);
      float Bp = __shfl_up(Bv, 16, 64);
      if (quad >= 1) { Bv = Av * Bp + Bv; Av = Ap * Av; }
      Ap = __shfl_up(Av, 32, 64);
      Bp = __shfl_up(Bv, 32, 64);
      if (quad >= 2) { Bv = Av * Bp + Bv; Av = Ap * Av; }
      qA[tm] = Av; qB[tm] = Bv;
    }
    if (quad == 3) {   // lane holds full 16-row composition per tm
      float CA = 1.0f, CB = 0.0f;
#pragma unroll
      for (int tm = 0; tm < 4; ++tm) { CB = qA[tm] * CB + qB[tm]; CA *= qA[tm]; }
      cA[(size_t)cidx * 1024 + j] = CA;
      cB[(size_t)cidx * 1024 + j] = CB;
    }
  }
}

// ---------------------------------------------------------------------------
// Plain GEMM (FC head): C[M,N] fp32 = A[M,K] f16 @ Bt[N,K]^T + bias
// ---------------------------------------------------------------------------
__global__ __launch_bounds__(256)
void gemm_f16_bt(const _Float16* __restrict__ A, const _Float16* __restrict__ Bt,
                 float* __restrict__ C, const float* __restrict__ bias,
                 int N, int K, int ntl2, int mt_per_x) {
  __shared__ _Float16 lds[4 * 128 * 32];
  const int tid  = threadIdx.x;
  const int lane = tid & 63;
  const int wave = tid >> 6;
  const int wm = wave >> 1, wn = wave & 1;
  const int quad = lane >> 4, r = lane & 15;
  int m0, n0;
  xcd_map(blockIdx.x, ntl2, mt_per_x, m0, n0);

  GemmCore core;
  core.init(A, Bt, lds, m0, n0, K, tid);
  fv4 acc[4][4] = {};
  core.run(acc, K);

  const int col0 = n0 + wn * 64 + r;
  const int row0 = m0 + wm * 64 + quad * 4;
#pragma unroll
  for (int tn = 0; tn < 4; ++tn) {
    const int col = col0 + tn * 16;
    const float bs = bias[col];
#pragma unroll
    for (int tm = 0; tm < 4; ++tm) {
#pragma unroll
      for (int r2 = 0; r2 < 4; ++r2) {
        C[(size_t)(row0 + tm * 16 + r2) * N + col] = acc[tm][tn][r2] + bs;
      }
    }
  }
}

// ---------------------------------------------------------------------------
// elementwise fp32 -> f16
// ---------------------------------------------------------------------------
__global__ void cvt_f16(const float* __restrict__ x, _Float16* __restrict__ y) {
  size_t i = ((size_t)blockIdx.x * 256 + threadIdx.x) * 4;
  fv4 v = *(const fv4*)(x + i);
  *(hv4*)(y + i) = __builtin_convertvector(v, hv4);
}

// ---------------------------------------------------------------------------
// W[K,N] fp32 -> Wt f16; cols j = bx*32+i -> output rows bx*mult + off + i.
// ---------------------------------------------------------------------------
__global__ void transpose_cvt(const float* __restrict__ W, _Float16* __restrict__ Wt,
                              int K, int N, int mult, int off) {
  __shared__ float tile[32][33];
  const int tx = threadIdx.x, ty = threadIdx.y;
  const int n  = blockIdx.x * 32 + tx;
  const int kb = blockIdx.y * 32;
  for (int i = ty; i < 32; i += 8)
    tile[i][tx] = W[(size_t)(kb + i) * N + n];
  __syncthreads();
  const int k = kb + tx;
  for (int i = ty; i < 32; i += 8)
    Wt[(size_t)(blockIdx.x * mult + off + i) * K + k] = (_Float16)tile[tx][i];
}

// ---------------------------------------------------------------------------
// phase B: wave-parallel Hillis-Steele over the 64 chunks (lane = chunk).
// hcy[c] = h entering chunk c (exclusive scan, h0 = 0).
// ---------------------------------------------------------------------------
__global__ void scan_phaseB(const float* __restrict__ cA, const float* __restrict__ cB,
                            float* __restrict__ hcy) {
  const int gtid = blockIdx.x * 256 + threadIdx.x;  // 2048 waves * 64
  const int lane = gtid & 63;
  const int wid  = gtid >> 6;
  const int h  = (wid & 255) * 4;
  const int bb = wid >> 8;
  const size_t o = (size_t)(bb * 64 + lane) * 1024 + h;
  fv4 Aa = *(const fv4*)(cA + o);
  fv4 Bv = *(const fv4*)(cB + o);
#pragma unroll
  for (int d = 1; d < 64; d <<= 1) {
    fv4 Ap, Bp;
#pragma unroll
    for (int k = 0; k < 4; ++k) {
      Ap[k] = __shfl_up(Aa[k], d, 64);
      Bp[k] = __shfl_up(Bv[k], d, 64);
    }
    if (lane >= d) {
      Bv = Aa * Bp + Bv;
      Aa = Ap * Aa;
    }
  }
  fv4 hc;
#pragma unroll
  for (int k = 0; k < 4; ++k) hc[k] = __shfl_up(Bv[k], 1, 64);
  if (lane == 0) { hc.x = 0.f; hc.y = 0.f; hc.z = 0.f; hc.w = 0.f; }
  *(fv4*)(hcy + o) = hc;
}

// phase C: replay chunk with correct carry, emit h (f16, [M,1024])
__global__ void scan_phaseC(const _Float16* __restrict__ zh2,
                            const float* __restrict__ hcy,
                            _Float16* __restrict__ hout) {
  const int idx = blockIdx.x * 256 + threadIdx.x;
  const int h  = (idx & 255) * 4;
  const int c  = (idx >> 8) & 63;
  const int bb = idx >> 14;
  const size_t base = ((size_t)(bb * 4096 + c * 64) * 1024 + h) * 2;
  const size_t ob   = (size_t)(bb * 4096 + c * 64) * 1024 + h;
  const size_t o    = (size_t)(bb * 64 + c) * 1024 + h;
  fv4 hc = *(const fv4*)(hcy + o);
#pragma unroll 4
  for (int t = 0; t < 64; ++t) {
    hv8 v = *(const hv8*)(zh2 + base + (size_t)t * 2048);
    fv4 av = __builtin_convertvector(__builtin_shufflevector(v, v, 0, 2, 4, 6), fv4);
    fv4 bv = __builtin_convertvector(__builtin_shufflevector(v, v, 1, 3, 5, 7), fv4);
    hc = av * hc + bv;
    *(hv4*)(hout + ob + (size_t)t * 1024) = __builtin_convertvector(hc, hv4);
  }
}

// ---------------------------------------------------------------------------
extern "C" void kernel_launch(void* const* d_in, const int* in_sizes, int n_in,
                              void* d_out, int out_size, void* d_ws, size_t ws_size,
                              hipStream_t stream) {
  const float* x   = (const float*)d_in[0];
  const float* Wz0 = (const float*)d_in[1];
  const float* bz0 = (const float*)d_in[2];
  const float* Wh0 = (const float*)d_in[3];
  const float* bh0 = (const float*)d_in[4];
  const float* Wz1 = (const float*)d_in[5];
  const float* bz1 = (const float*)d_in[6];
  const float* Wh1 = (const float*)d_in[7];
  const float* bh1 = (const float*)d_in[8];
  const float* Wfc = (const float*)d_in[9];
  const float* bfc = (const float*)d_in[10];

  const int Mrows = 32768;  // B*T
  const int H = 1024, Din = 512, Dout = 512;

  // workspace layout (~205 MiB)
  char* w = (char*)d_ws;
  _Float16* zh2   = (_Float16*)w; w += (size_t)Mrows * 2 * H * 2;   // 128 MiB
  _Float16* hx    = (_Float16*)w; w += (size_t)Mrows * H * 2;       //  64 MiB
  _Float16* Wzh0t = (_Float16*)w; w += (size_t)2 * H * Din * 2;
  _Float16* Wzh1t = (_Float16*)w; w += (size_t)2 * H * H * 2;
  _Float16* Wft   = (_Float16*)w; w += (size_t)Dout * H * 2;
  float*    cA    = (float*)w;    w += (size_t)8 * 64 * H * 4;
  float*    cB    = (float*)w;    w += (size_t)8 * 64 * H * 4;
  float*    hcy   = (float*)w;    w += (size_t)8 * 64 * H * 4;
  _Float16* Xb    = hx;  // aliased: x(f16) dead before h0 is written

  // --- input conversions (fused z|h row mapping for layer weights) ---
  cvt_f16<<<Mrows * Din / 1024, 256, 0, stream>>>(x, Xb);
  transpose_cvt<<<dim3(H / 32, Din / 32), dim3(32, 8), 0, stream>>>(Wz0, Wzh0t, Din, H, 64, 0);
  transpose_cvt<<<dim3(H / 32, Din / 32), dim3(32, 8), 0, stream>>>(Wh0, Wzh0t, Din, H, 64, 32);
  transpose_cvt<<<dim3(H / 32, H / 32),   dim3(32, 8), 0, stream>>>(Wz1, Wzh1t, H, H, 64, 0);
  transpose_cvt<<<dim3(H / 32, H / 32),   dim3(32, 8), 0, stream>>>(Wh1, Wzh1t, H, H, 64, 32);
  transpose_cvt<<<dim3(Dout / 32, H / 32), dim3(32, 8), 0, stream>>>(Wfc, Wft, H, Dout, 32, 0);

  // layer GEMM: 4096 blocks, ntiles=16 (ntl2=4), 256 mtiles -> 32 per XCD
  // --- layer 0 ---
  gemm_gate<<<4096, 256, 0, stream>>>(Xb, Wzh0t, zh2, cA, cB, bz0, bh0, Din, 4, 32);
  scan_phaseB<<<512, 256, 0, stream>>>(cA, cB, hcy);
  scan_phaseC<<<512, 256, 0, stream>>>(zh2, hcy, hx);

  // --- layer 1 ---
  gemm_gate<<<4096, 256, 0, stream>>>(hx, Wzh1t, zh2, cA, cB, bz1, bh1, H, 4, 32);
  scan_phaseB<<<512, 256, 0, stream>>>(cA, cB, hcy);
  scan_phaseC<<<512, 256, 0, stream>>>(zh2, hcy, hx);

  // --- FC head: 1024 blocks, ntiles=4 (ntl2=2), 256 mtiles -> 32 per XCD ---
  gemm_f16_bt<<<1024, 256, 0, stream>>>(hx, Wft, (float*)d_out, bfc, Dout, H, 2, 32);
}